// Round 4
// baseline (823.165 us; speedup 1.0000x reference)
//
#include <hip/hip_runtime.h>

typedef unsigned long long u64;
typedef unsigned int u32;
typedef _Float16 f16;
typedef _Float16 f16x8 __attribute__((ext_vector_type(8)));
typedef float f32x4 __attribute__((ext_vector_type(4)));

#define MFMA16(a, b, c) __builtin_amdgcn_mfma_f32_16x16x32_f16(a, b, c, 0, 0, 0)

#define NROWS 32768
#define DIN   1024
#define DM    512
#define KC    1024
#define SPLIT_SC  1024.0f
#define SPLIT_INV 0.0009765625f
#define CHSZ  32
#define MAXCH 2048

// ---- output float offsets ----
#define OFF_XR   0ull
#define OFF_CL   33554432ull
#define OFF_IDX  33554433ull
#define OFF_ZE   33587201ull   // base %4==1 -> scalar access only
#define OFF_ZQ   50364417ull
#define OFF_NE   67141633ull
#define OFF_NCS  67665921ull
#define OFF_NEMA 67666945ull

// ---- workspace byte offsets ----
#define WS_ROWMIN  2097152ull  // u64[32768]
#define WS_IDX     2490368ull
#define WS_COUNTS  2621440ull
#define WS_STARTS  2625536ull
#define WS_OFFW    2629632ull
#define WS_ROWLIST 2633728ull
#define WS_CSD     2764800ull
#define WS_CACC    2768896ull
#define WS_ENORM   2769920ull
#define WS2_ZQ16   (4ull<<20)
#define WS2_WT1    (36ull<<20)
#define WS2_WT2    (37ull<<20)
#define WS2_DT     (38ull<<20)
#define WS2_E1     (39ull<<20)
#define WS2_E2     (40ull<<20)
#define WS3_CHPFX  (41ull<<20)
#define WS3_CHCODE ((41ull<<20) + 8192)
#define WS3_PART   ((41ull<<20) + 65536)

// ============================================================================
// LDS helpers. Planes: BK=32 -> [128][32] f16 (8KB), chunk swz kc^((r>>1)&3);
//                      BK=64 -> [128][64] f16 (16KB), chunk swz kc^(r&7).
// global_load_lds: linear LDS dest (base + lane*16), inverse-swizzled global src.
// ============================================================================
__device__ inline void gload16(const f16* g, f16* l) {
  __builtin_amdgcn_global_load_lds((const __attribute__((address_space(1))) void*)g,
                                   (__attribute__((address_space(3))) void*)l, 16, 0, 0);
}

__device__ inline f16x8 ldfrag32(const f16* p, int row, int kc) {
  return *(const f16x8*)(p + row * 32 + ((kc ^ ((row >> 1) & 3)) << 3));
}
__device__ inline f16x8 ldfrag64(const f16* p, int row, int kc) {
  return *(const f16x8*)(p + row * 64 + ((kc ^ (row & 7)) << 3));
}

// stage a [128][32] f16 plane (8KB) with 512 threads: 1x 16B gload_lds each
__device__ inline void stage32(const f16* gbase, int ld, int row0, int k0,
                               f16* lds, int t) {
  int r = t >> 2, c = t & 3;
  int cs = c ^ ((r >> 1) & 3);
  gload16(gbase + (size_t)(row0 + r) * ld + k0 + cs * 8, lds + t * 8);
}

// stage a [128][64] f16 plane (16KB) with 512 threads: 2x 16B gload_lds each
__device__ inline void stage64(const f16* gbase, int ld, int row0, int k0,
                               f16* lds, int t) {
#pragma unroll
  for (int h = 0; h < 2; h++) {
    int e = t + h * 512;
    int r = e >> 3, c = e & 7;
    int cs = c ^ (r & 7);
    gload16(gbase + (size_t)(row0 + r) * ld + k0 + cs * 8, lds + e * 8);
  }
}

#define BAR1_V4   { asm volatile("s_waitcnt vmcnt(4)" ::: "memory"); \
                    __builtin_amdgcn_sched_barrier(0); \
                    __builtin_amdgcn_s_barrier(); \
                    asm volatile("" ::: "memory"); }
#define BAR1_V4L0 { asm volatile("s_waitcnt vmcnt(4) lgkmcnt(0)" ::: "memory"); \
                    __builtin_amdgcn_sched_barrier(0); \
                    __builtin_amdgcn_s_barrier(); \
                    asm volatile("" ::: "memory"); }
#define BAR1_V0L0 { asm volatile("s_waitcnt vmcnt(0) lgkmcnt(0)" ::: "memory"); \
                    __builtin_amdgcn_sched_barrier(0); \
                    __builtin_amdgcn_s_barrier(); \
                    asm volatile("" ::: "memory"); }
#define BAR2      { asm volatile("s_waitcnt lgkmcnt(0)" ::: "memory"); \
                    __builtin_amdgcn_s_barrier(); \
                    asm volatile("" ::: "memory"); }

// ============================================================================
// prep kernels
// ============================================================================
__global__ __launch_bounds__(256) void k_init(u64* __restrict__ rowmin,
                                              int* __restrict__ counts,
                                              float* __restrict__ cacc) {
  int i = blockIdx.x * 256 + threadIdx.x;
  rowmin[i] = ~0ull;
  if (i < KC) counts[i] = 0;
  if (i == 0) cacc[0] = 0.f;
}

__global__ __launch_bounds__(256) void k_prept(const float* __restrict__ W,
                                               f16* __restrict__ o1,
                                               f16* __restrict__ o2,
                                               int K, int N) {
  __shared__ float tile[32][33];
  int tx = threadIdx.x & 31, ty = threadIdx.x >> 5;
  int nb = blockIdx.x * 32, kb = blockIdx.y * 32;
#pragma unroll
  for (int i = 0; i < 32; i += 8)
    tile[ty + i][tx] = W[(size_t)(kb + ty + i) * N + nb + tx];
  __syncthreads();
#pragma unroll
  for (int i = 0; i < 32; i += 8) {
    float v = tile[tx][ty + i];
    f16 h = (f16)v;
    size_t o = (size_t)(nb + ty + i) * K + kb + tx;
    o1[o] = h;
    if (o2) o2[o] = (f16)((v - (float)h) * SPLIT_SC);
  }
}

__global__ __launch_bounds__(256) void k_prepe(const float* __restrict__ E,
                                               f16* __restrict__ e1,
                                               f16* __restrict__ e2) {
  int tid = blockIdx.x * 256 + threadIdx.x;
  for (int i = tid; i < KC * DM; i += 131072) {
    float v = E[i];
    f16 h = (f16)v;
    e1[i] = h;
    e2[i] = (f16)((v - (float)h) * SPLIT_SC);
  }
}

__global__ __launch_bounds__(64) void k_enorm(const float* __restrict__ E,
                                              float* __restrict__ enorm) {
  int k = blockIdx.x, t = threadIdx.x;
  float s = 0.f;
#pragma unroll
  for (int j = 0; j < 8; j++) {
    float v = E[(size_t)k * DM + t + j * 64];
    s = fmaf(v, v, s);
  }
#pragma unroll
  for (int m = 1; m < 64; m <<= 1) s += __shfl_xor(s, m, 64);
  if (t == 0) enorm[k] = s;
}

// ============================================================================
// encoder GEMM: 128x128 tile, BK=32, B via gload_lds dbuf, A reg-staged
// grid 1024 (4 ct x 256 panels), XCD-swizzled
// ============================================================================
__global__ __launch_bounds__(512) void k_genc2(const float* __restrict__ x,
                                               const f16* __restrict__ wt1,
                                               const f16* __restrict__ wt2,
                                               const float* __restrict__ bias,
                                               float* __restrict__ dst) {
  __shared__ __align__(16) f16 A1[128 * 32], A2[128 * 32];
  __shared__ __align__(16) f16 B1[2][128 * 32], B2[2][128 * 32];
  int t = threadIdx.x, lane = t & 63, wid = t >> 6;
  int wm = wid >> 2, wn = wid & 3;
  int l = blockIdx.x;
  int xcd = l & 7, s = l >> 3, ct = s & 3;
  int p = ((s >> 2) << 3) | xcd;
  int m0 = p * 128, n0 = ct * 128;
  int r = t >> 2, cg = t & 3;
  int cslot = cg ^ ((r >> 1) & 3);
  const float* ax = x + (size_t)(m0 + r) * DIN + cg * 8;
  f32x4 accA[4][2] = {}, accB[4][2] = {};

  // prologue: A(0) regs + B(0) LDS
  float4 av0 = *(const float4*)(ax);
  float4 av1 = *(const float4*)(ax + 4);
  stage32(wt1, DIN, n0, 0, B1[0], t);
  stage32(wt2, DIN, n0, 0, B2[0], t);
  int cur = 0;

  for (int it = 0; it < 32; ++it) {
    float4 nv0 = av0, nv1 = av1;
    if (it < 31) {
      int k0n = (it + 1) * 32;
      stage32(wt1, DIN, n0, k0n, B1[cur ^ 1], t);
      stage32(wt2, DIN, n0, k0n, B2[cur ^ 1], t);
      nv0 = *(const float4*)(ax + k0n);
      nv1 = *(const float4*)(ax + k0n + 4);
      asm volatile("s_waitcnt vmcnt(4)" ::: "memory");
    } else {
      asm volatile("s_waitcnt vmcnt(0)" ::: "memory");
    }
    // convert current A -> LDS (single-buffered: safe, prev compute barrier'd)
    {
      float a[8] = {av0.x, av0.y, av0.z, av0.w, av1.x, av1.y, av1.z, av1.w};
      f16 h1[8], h2[8];
#pragma unroll
      for (int j = 0; j < 8; j++) {
        f16 h = (f16)a[j];
        h1[j] = h;
        h2[j] = (f16)((a[j] - (float)h) * SPLIT_SC);
      }
      *(f16x8*)(A1 + r * 32 + cslot * 8) = *(f16x8*)h1;
      *(f16x8*)(A2 + r * 32 + cslot * 8) = *(f16x8*)h2;
    }
    asm volatile("s_waitcnt lgkmcnt(0)" ::: "memory");
    __builtin_amdgcn_sched_barrier(0);
    __builtin_amdgcn_s_barrier();
    asm volatile("" ::: "memory");
    {
      int kc = lane >> 4;
      f16x8 a1f[4], a2f[4], b1f[2], b2f[2];
#pragma unroll
      for (int m = 0; m < 4; m++) {
        int row = wm * 64 + m * 16 + (lane & 15);
        a1f[m] = ldfrag32(A1, row, kc);
        a2f[m] = ldfrag32(A2, row, kc);
      }
#pragma unroll
      for (int n = 0; n < 2; n++) {
        int row = wn * 32 + n * 16 + (lane & 15);
        b1f[n] = ldfrag32(B1[cur], row, kc);
        b2f[n] = ldfrag32(B2[cur], row, kc);
      }
#pragma unroll
      for (int m = 0; m < 4; m++)
#pragma unroll
        for (int n = 0; n < 2; n++) {
          accA[m][n] = MFMA16(a1f[m], b1f[n], accA[m][n]);
          accB[m][n] = MFMA16(a1f[m], b2f[n], accB[m][n]);
          accB[m][n] = MFMA16(a2f[m], b1f[n], accB[m][n]);
        }
    }
    BAR2;
    av0 = nv0; av1 = nv1; cur ^= 1;
  }
#pragma unroll
  for (int m = 0; m < 4; m++)
#pragma unroll
    for (int n = 0; n < 2; n++)
#pragma unroll
      for (int j = 0; j < 4; j++) {
        int row = m0 + wm * 64 + m * 16 + (lane >> 4) * 4 + j;
        int col = n0 + wn * 32 + n * 16 + (lane & 15);
        dst[(size_t)row * DM + col] = accA[m][n][j] + SPLIT_INV * accB[m][n][j] + bias[col];
      }
}

// ============================================================================
// distance GEMM + argmin: 2048 blocks (8 ct x 256 panels, same-XCD panels),
// BK=32, all 4 planes gload_lds dbuf, global u64 atomicMin
// ============================================================================
__global__ __launch_bounds__(512) void k_dist2(const f16* __restrict__ z1,
                                               const f16* __restrict__ z2,
                                               const f16* __restrict__ e1,
                                               const f16* __restrict__ e2,
                                               const float* __restrict__ enorm,
                                               u64* __restrict__ rowmin) {
  __shared__ __align__(16) f16 A1[2][128 * 32], A2[2][128 * 32];
  __shared__ __align__(16) f16 B1[2][128 * 32], B2[2][128 * 32];
  int t = threadIdx.x, lane = t & 63, wid = t >> 6;
  int wm = wid >> 2, wn = wid & 3;
  int l = blockIdx.x;
  int xcd = l & 7, s = l >> 3, ct = s & 7;
  int p = ((s >> 3) << 3) | xcd;
  int r0 = p * 128, c0 = ct * 128;
  f32x4 accA[4][2] = {}, accB[4][2] = {};

  stage32(z1, DM, r0, 0, A1[0], t);
  stage32(z2, DM, r0, 0, A2[0], t);
  stage32(e1, DM, c0, 0, B1[0], t);
  stage32(e2, DM, c0, 0, B2[0], t);
  int cur = 0;

  for (int it = 0; it < 16; ++it) {
    if (it < 15) {
      int k0n = (it + 1) * 32;
      stage32(z1, DM, r0, k0n, A1[cur ^ 1], t);
      stage32(z2, DM, r0, k0n, A2[cur ^ 1], t);
      stage32(e1, DM, c0, k0n, B1[cur ^ 1], t);
      stage32(e2, DM, c0, k0n, B2[cur ^ 1], t);
      BAR1_V4;
    } else {
      BAR1_V0L0;
    }
    {
      int kc = lane >> 4;
      f16x8 a1f[4], a2f[4], b1f[2], b2f[2];
#pragma unroll
      for (int m = 0; m < 4; m++) {
        int row = wm * 64 + m * 16 + (lane & 15);
        a1f[m] = ldfrag32(A1[cur], row, kc);
        a2f[m] = ldfrag32(A2[cur], row, kc);
      }
#pragma unroll
      for (int n = 0; n < 2; n++) {
        int row = wn * 32 + n * 16 + (lane & 15);
        b1f[n] = ldfrag32(B1[cur], row, kc);
        b2f[n] = ldfrag32(B2[cur], row, kc);
      }
#pragma unroll
      for (int m = 0; m < 4; m++)
#pragma unroll
        for (int n = 0; n < 2; n++) {
          accA[m][n] = MFMA16(a1f[m], b1f[n], accA[m][n]);
          accB[m][n] = MFMA16(a1f[m], b2f[n], accB[m][n]);
          accB[m][n] = MFMA16(a2f[m], b1f[n], accB[m][n]);
        }
    }
    BAR2;
    cur ^= 1;
  }

  float en0 = enorm[c0 + wn * 32 + (lane & 15)];
  float en1 = enorm[c0 + wn * 32 + 16 + (lane & 15)];
#pragma unroll
  for (int m = 0; m < 4; m++)
#pragma unroll
    for (int j = 0; j < 4; j++) {
      int r_l = wm * 64 + m * 16 + (lane >> 4) * 4 + j;
      u64 best = ~0ull;
#pragma unroll
      for (int n = 0; n < 2; n++) {
        int col = c0 + wn * 32 + n * 16 + (lane & 15);
        float dot = accA[m][n][j] + SPLIT_INV * accB[m][n][j];
        float sc = fmaf(-2.0f, dot, n ? en1 : en0);
        u32 kb = __float_as_uint(sc);
        kb = (kb & 0x80000000u) ? ~kb : (kb | 0x80000000u);
        u64 pk = ((u64)kb << 32) | (u32)col;
        best = pk < best ? pk : best;
      }
#pragma unroll
      for (int msk = 1; msk < 16; msk <<= 1) {
        u64 o = __shfl_xor(best, msk, 64);
        best = o < best ? o : best;
      }
      if ((lane & 15) == 0) atomicMin(rowmin + r0 + r_l, best);
    }
}

// ============================================================================
// decoder GEMM: BK=64, all-f16 gload_lds dbuf, 2048 blocks XCD-swizzled
// ============================================================================
__global__ __launch_bounds__(512) void k_gdec2(const f16* __restrict__ zq16,
                                               const f16* __restrict__ dT,
                                               const float* __restrict__ bias,
                                               float* __restrict__ dst) {
  __shared__ __align__(16) f16 A1[2][128 * 64], B1[2][128 * 64];
  int t = threadIdx.x, lane = t & 63, wid = t >> 6;
  int wm = wid >> 2, wn = wid & 3;
  int l = blockIdx.x;
  int xcd = l & 7, s = l >> 3, ct = s & 7;
  int p = ((s >> 3) << 3) | xcd;
  int m0 = p * 128, n0 = ct * 128;
  f32x4 acc[4][2] = {};

  stage64(zq16, DM, m0, 0, A1[0], t);
  stage64(dT, DM, n0, 0, B1[0], t);
  int cur = 0;

  for (int it = 0; it < 8; ++it) {
    if (it < 7) {
      int k0n = (it + 1) * 64;
      stage64(zq16, DM, m0, k0n, A1[cur ^ 1], t);
      stage64(dT, DM, n0, k0n, B1[cur ^ 1], t);
      BAR1_V4;
    } else {
      BAR1_V0L0;
    }
#pragma unroll
    for (int kk = 0; kk < 2; kk++) {
      int kc = kk * 4 + (lane >> 4);
      f16x8 a1f[4], b1f[2];
#pragma unroll
      for (int m = 0; m < 4; m++)
        a1f[m] = ldfrag64(A1[cur], wm * 64 + m * 16 + (lane & 15), kc);
#pragma unroll
      for (int n = 0; n < 2; n++)
        b1f[n] = ldfrag64(B1[cur], wn * 32 + n * 16 + (lane & 15), kc);
#pragma unroll
      for (int m = 0; m < 4; m++)
#pragma unroll
        for (int n = 0; n < 2; n++) acc[m][n] = MFMA16(a1f[m], b1f[n], acc[m][n]);
    }
    BAR2;
    cur ^= 1;
  }
#pragma unroll
  for (int m = 0; m < 4; m++)
#pragma unroll
    for (int n = 0; n < 2; n++)
#pragma unroll
      for (int j = 0; j < 4; j++) {
        int row = m0 + wm * 64 + m * 16 + (lane >> 4) * 4 + j;
        int col = n0 + wn * 32 + n * 16 + (lane & 15);
        dst[(size_t)row * DIN + col] = acc[m][n][j] + bias[col];
      }
}

// ============================================================================
// gather: z_q (fp32 + f16), indices, histogram, commit-loss partials
// ============================================================================
__global__ __launch_bounds__(128) void k_gather(const u64* __restrict__ rowmin,
                                                const float* __restrict__ E,
                                                float* __restrict__ out,
                                                int* __restrict__ idxws,
                                                int* __restrict__ counts,
                                                float* __restrict__ cacc,
                                                f16* __restrict__ zq16) {
  int r = blockIdx.x, t = threadIdx.x;
  int idx = (int)(u32)(rowmin[r] & 0xffffffffull);
  const float* ze = out + OFF_ZE + (size_t)r * DM;
  float* zq = out + OFF_ZQ + (size_t)r * DM;
  f16* zp = zq16 + (size_t)r * DM;
  const float* e = E + (size_t)idx * DM;
  float loc = 0.f;
#pragma unroll
  for (int j = 0; j < 4; j++) {
    int c = t + j * 128;
    float z = ze[c], q = e[c];
    zq[c] = q;
    zp[c] = (f16)q;
    float d = z - q;
    loc = fmaf(d, d, loc);
  }
#pragma unroll
  for (int m = 1; m < 64; m <<= 1) loc += __shfl_xor(loc, m, 64);
  __shared__ float sh[2];
  if ((t & 63) == 0) sh[t >> 6] = loc;
  __syncthreads();
  if (t == 0) {
    atomicAdd(cacc, sh[0] + sh[1]);
    atomicAdd(counts + idx, 1);
    out[OFF_IDX + r] = (float)idx;
    idxws[r] = idx;
  }
}

// ============================================================================
// LayerNorm + f16 split planes of z_e
// ============================================================================
__global__ __launch_bounds__(256) void k_ln2(float* __restrict__ ze,
                                             const float* __restrict__ g,
                                             const float* __restrict__ b,
                                             f16* __restrict__ z1,
                                             f16* __restrict__ z2) {
  int t = threadIdx.x, lane = t & 63, wid = t >> 6;
  int R = blockIdx.x * 4 + wid;
  float* row = ze + (size_t)R * DM;
  float v[8];
  float s = 0.f, sq = 0.f;
#pragma unroll
  for (int j = 0; j < 8; j++) {
    v[j] = row[lane + j * 64];
    s += v[j];
    sq = fmaf(v[j], v[j], sq);
  }
#pragma unroll
  for (int m = 1; m < 64; m <<= 1) {
    s += __shfl_xor(s, m, 64);
    sq += __shfl_xor(sq, m, 64);
  }
  float mu = s * (1.f / DM);
  float var = sq * (1.f / DM) - mu * mu;
  float rs = rsqrtf(var + 1e-5f);
#pragma unroll
  for (int j = 0; j < 8; j++) {
    int c = lane + j * 64;
    float o = (v[j] - mu) * rs * g[c] + b[c];
    row[c] = o;
    f16 h = (f16)o;
    z1[(size_t)R * DM + c] = h;
    z2[(size_t)R * DM + c] = (f16)((o - (float)h) * SPLIT_SC);
  }
}

// ============================================================================
// EMA tail (balanced chunked segment-sum, proven round 3)
// ============================================================================
__global__ __launch_bounds__(1024) void k_scan(const int* __restrict__ counts,
                                               const float* __restrict__ cs_in,
                                               float* __restrict__ out,
                                               int* __restrict__ starts,
                                               int* __restrict__ offw,
                                               float* __restrict__ csd,
                                               const float* __restrict__ cacc,
                                               int* __restrict__ chpfx,
                                               int* __restrict__ chcode) {
  __shared__ float f[1024];
  __shared__ int ib[1024];
  int t = threadIdx.x;
  int cnt = counts[t];
  float ncs = 0.99f * cs_in[t] + 0.01f * (float)cnt;
  out[OFF_NCS + t] = ncs;
  f[t] = ncs;
  __syncthreads();
  for (int s = 512; s > 0; s >>= 1) {
    if (t < s) f[t] += f[t + s];
    __syncthreads();
  }
  float n = f[0];
  csd[t] = (ncs + 1e-5f) / (n + (float)KC * 1e-5f) * n;
  ib[t] = cnt;
  __syncthreads();
  for (int s = 1; s < 1024; s <<= 1) {
    int y = (t >= s) ? ib[t - s] : 0;
    __syncthreads();
    ib[t] += y;
    __syncthreads();
  }
  int excl = ib[t] - cnt;
  starts[t] = excl;
  offw[t] = excl;
  if (t == 0) out[OFF_CL] = cacc[0] * (1.f / ((float)NROWS * (float)DM));
  int nch = (cnt + CHSZ - 1) / CHSZ;
  __syncthreads();
  ib[t] = nch;
  __syncthreads();
  for (int s = 1; s < 1024; s <<= 1) {
    int y = (t >= s) ? ib[t - s] : 0;
    __syncthreads();
    ib[t] += y;
    __syncthreads();
  }
  int chx = ib[t] - nch;
  chpfx[t] = chx;
  if (t == KC - 1) chpfx[KC] = ib[t];
  for (int j = 0; j < nch; j++) chcode[chx + j] = t;
}

__global__ __launch_bounds__(256) void k_scatter(const int* __restrict__ idxws,
                                                 int* __restrict__ offw,
                                                 int* __restrict__ rowlist) {
  int r = blockIdx.x * 256 + threadIdx.x;
  int idx = idxws[r];
  int pos = atomicAdd(offw + idx, 1);
  rowlist[pos] = r;
}

__global__ __launch_bounds__(128) void k_partsum(const int* __restrict__ chpfx,
                                                 const int* __restrict__ chcode,
                                                 const int* __restrict__ starts,
                                                 const int* __restrict__ counts,
                                                 const int* __restrict__ rowlist,
                                                 const float* __restrict__ out,
                                                 float* __restrict__ part) {
  int c = blockIdx.x, t = threadIdx.x;
  if (c >= chpfx[KC]) return;
  int code = chcode[c];
  int j = c - chpfx[code];
  int ofs = starts[code] + j * CHSZ;
  int len = min(CHSZ, counts[code] - j * CHSZ);
  __shared__ int rl[CHSZ];
  if (t < len) rl[t] = rowlist[ofs + t];
  __syncthreads();
  const float* zeb = out + OFF_ZE;
  float a0 = 0.f, a1 = 0.f, a2 = 0.f, a3 = 0.f;
  for (int i = 0; i < len; i++) {
    const float* z = zeb + (size_t)rl[i] * DM;
    a0 += z[t];
    a1 += z[t + 128];
    a2 += z[t + 256];
    a3 += z[t + 384];
  }
  float* pp = part + (size_t)c * DM;
  pp[t] = a0;
  pp[t + 128] = a1;
  pp[t + 256] = a2;
  pp[t + 384] = a3;
}

__global__ __launch_bounds__(128) void k_codesum2(const int* __restrict__ chpfx,
                                                  const float* __restrict__ part,
                                                  const float* __restrict__ ema_in,
                                                  const float* __restrict__ csd,
                                                  float* __restrict__ out) {
  int k = blockIdx.x, t = threadIdx.x;
  int base = chpfx[k], nch = chpfx[k + 1] - base;
  float a0 = 0.f, a1 = 0.f, a2 = 0.f, a3 = 0.f;
  for (int i = 0; i < nch; i++) {
    const float* pp = part + (size_t)(base + i) * DM;
    a0 += pp[t];
    a1 += pp[t + 128];
    a2 += pp[t + 256];
    a3 += pp[t + 384];
  }
  float cs = csd[k];
  float sum[4] = {a0, a1, a2, a3};
#pragma unroll
  for (int j = 0; j < 4; j++) {
    int c = t + j * 128;
    float e = 0.99f * ema_in[(size_t)k * DM + c] + 0.01f * sum[j];
    out[OFF_NEMA + (size_t)k * DM + c] = e;
    out[OFF_NE + (size_t)k * DM + c] = e / cs;
  }
}

// ============================================================================
extern "C" void kernel_launch(void* const* d_in, const int* in_sizes, int n_in,
                              void* d_out, int out_size, void* d_ws, size_t ws_size,
                              hipStream_t stream) {
  (void)in_sizes; (void)n_in; (void)out_size; (void)ws_size;
  const float* x = (const float*)d_in[0];
  const float* enc_w = (const float*)d_in[1];
  const float* enc_b = (const float*)d_in[2];
  const float* ln_g = (const float*)d_in[3];
  const float* ln_b = (const float*)d_in[4];
  const float* dec_w = (const float*)d_in[5];
  const float* dec_b = (const float*)d_in[6];
  const float* emb = (const float*)d_in[7];
  const float* cs_in = (const float*)d_in[8];
  const float* ema_in = (const float*)d_in[9];
  float* out = (float*)d_out;
  char* ws = (char*)d_ws;
  u64* rowmin = (u64*)(ws + WS_ROWMIN);
  int* idxws = (int*)(ws + WS_IDX);
  int* counts = (int*)(ws + WS_COUNTS);
  int* starts = (int*)(ws + WS_STARTS);
  int* offw = (int*)(ws + WS_OFFW);
  int* rowlist = (int*)(ws + WS_ROWLIST);
  float* csd = (float*)(ws + WS_CSD);
  float* cacc = (float*)(ws + WS_CACC);
  float* enorm = (float*)(ws + WS_ENORM);
  f16* zq16 = (f16*)(ws + WS2_ZQ16);
  f16* wt1 = (f16*)(ws + WS2_WT1);
  f16* wt2 = (f16*)(ws + WS2_WT2);
  f16* dT = (f16*)(ws + WS2_DT);
  f16* e1 = (f16*)(ws + WS2_E1);
  f16* e2 = (f16*)(ws + WS2_E2);
  int* chpfx = (int*)(ws + WS3_CHPFX);
  int* chcode = (int*)(ws + WS3_CHCODE);
  float* part = (float*)(ws + WS3_PART);
  f16* z1 = (f16*)out;                 // scratch in x_recon region (overwritten by k_gdec2)
  f16* z2 = z1 + (size_t)NROWS * DM;

  k_init<<<dim3(NROWS / 256), dim3(256), 0, stream>>>(rowmin, counts, cacc);
  k_prept<<<dim3(16, 32), dim3(256), 0, stream>>>(enc_w, wt1, wt2, DIN, DM);
  k_prept<<<dim3(32, 16), dim3(256), 0, stream>>>(dec_w, dT, nullptr, DM, DIN);
  k_prepe<<<dim3(512), dim3(256), 0, stream>>>(emb, e1, e2);
  k_enorm<<<dim3(KC), dim3(64), 0, stream>>>(emb, enorm);
  k_genc2<<<dim3(1024), dim3(512), 0, stream>>>(x, wt1, wt2, enc_b, out + OFF_ZE);
  k_ln2<<<dim3(8192), dim3(256), 0, stream>>>(out + OFF_ZE, ln_g, ln_b, z1, z2);
  k_dist2<<<dim3(2048), dim3(512), 0, stream>>>(z1, z2, e1, e2, enorm, rowmin);
  k_gather<<<dim3(NROWS), dim3(128), 0, stream>>>(rowmin, emb, out, idxws, counts, cacc, zq16);
  k_scan<<<dim3(1), dim3(1024), 0, stream>>>(counts, cs_in, out, starts, offw, csd,
                                             cacc, chpfx, chcode);
  k_scatter<<<dim3(NROWS / 256), dim3(256), 0, stream>>>(idxws, offw, rowlist);
  k_partsum<<<dim3(MAXCH), dim3(128), 0, stream>>>(chpfx, chcode, starts, counts,
                                                   rowlist, out, part);
  k_codesum2<<<dim3(KC), dim3(128), 0, stream>>>(chpfx, part, ema_in, csd, out);
  k_gdec2<<<dim3(2048), dim3(512), 0, stream>>>(zq16, dT, dec_b, out + OFF_XR);
}

// Round 5
// 444.610 us; speedup vs baseline: 1.8514x; 1.8514x over previous
//
#include <hip/hip_runtime.h>

typedef unsigned long long u64;
typedef unsigned int u32;
typedef _Float16 f16;
typedef _Float16 f16x8 __attribute__((ext_vector_type(8)));
typedef float f32x4 __attribute__((ext_vector_type(4)));

#define MFMA16(a, b, c) __builtin_amdgcn_mfma_f32_16x16x32_f16(a, b, c, 0, 0, 0)

#define NROWS 32768
#define DIN   1024
#define DM    512
#define KC    1024
#define SPLIT_SC  1024.0f
#define SPLIT_INV 0.0009765625f
#define CHSZ  32
#define MAXCH 2048
#define GROWS 16

// ---- output float offsets ----
#define OFF_XR   0ull
#define OFF_CL   33554432ull
#define OFF_IDX  33554433ull
#define OFF_ZE   33587201ull   // base %4==1 -> scalar access only
#define OFF_ZQ   50364417ull
#define OFF_NE   67141633ull
#define OFF_NCS  67665921ull
#define OFF_NEMA 67666945ull

// ---- workspace byte offsets ----
#define WS_ROWMIN  2097152ull  // u64[32768]
#define WS_IDX     2490368ull
#define WS_COUNTS  2621440ull
#define WS_STARTS  2625536ull
#define WS_OFFW    2629632ull
#define WS_ROWLIST 2633728ull
#define WS_CSD     2764800ull
#define WS_CACC    2768896ull
#define WS_ENORM   2769920ull
#define WS2_ZQ16   (4ull<<20)
#define WS2_WT1    (36ull<<20)
#define WS2_WT2    (37ull<<20)
#define WS2_DT     (38ull<<20)
#define WS2_E1     (39ull<<20)
#define WS2_E2     (40ull<<20)
#define WS3_CHPFX  (41ull<<20)
#define WS3_CHCODE ((41ull<<20) + 8192)
#define WS3_CPART  ((41ull<<20) + 16384)   // float[2048] commit-loss partials
#define WS3_PART   ((41ull<<20) + 65536)

// ============================================================================
// LDS helpers. Planes: BK=32 -> [128][32] f16 (8KB), chunk swz kc^((r>>1)&3);
//                      BK=64 -> [128][64] f16 (16KB), chunk swz kc^(r&7).
// global_load_lds: linear LDS dest (base + lane*16), inverse-swizzled global src.
// ============================================================================
__device__ inline void gload16(const f16* g, f16* l) {
  __builtin_amdgcn_global_load_lds((const __attribute__((address_space(1))) void*)g,
                                   (__attribute__((address_space(3))) void*)l, 16, 0, 0);
}

__device__ inline f16x8 ldfrag32(const f16* p, int row, int kc) {
  return *(const f16x8*)(p + row * 32 + ((kc ^ ((row >> 1) & 3)) << 3));
}
__device__ inline f16x8 ldfrag64(const f16* p, int row, int kc) {
  return *(const f16x8*)(p + row * 64 + ((kc ^ (row & 7)) << 3));
}

__device__ inline void stage32(const f16* gbase, int ld, int row0, int k0,
                               f16* lds, int t) {
  int r = t >> 2, c = t & 3;
  int cs = c ^ ((r >> 1) & 3);
  gload16(gbase + (size_t)(row0 + r) * ld + k0 + cs * 8, lds + t * 8);
}

__device__ inline void stage64(const f16* gbase, int ld, int row0, int k0,
                               f16* lds, int t) {
#pragma unroll
  for (int h = 0; h < 2; h++) {
    int e = t + h * 512;
    int r = e >> 3, c = e & 7;
    int cs = c ^ (r & 7);
    gload16(gbase + (size_t)(row0 + r) * ld + k0 + cs * 8, lds + e * 8);
  }
}

#define BAR1_V4   { asm volatile("s_waitcnt vmcnt(4)" ::: "memory"); \
                    __builtin_amdgcn_sched_barrier(0); \
                    __builtin_amdgcn_s_barrier(); \
                    asm volatile("" ::: "memory"); }
#define BAR1_V0L0 { asm volatile("s_waitcnt vmcnt(0) lgkmcnt(0)" ::: "memory"); \
                    __builtin_amdgcn_sched_barrier(0); \
                    __builtin_amdgcn_s_barrier(); \
                    asm volatile("" ::: "memory"); }
#define BAR2      { asm volatile("s_waitcnt lgkmcnt(0)" ::: "memory"); \
                    __builtin_amdgcn_s_barrier(); \
                    asm volatile("" ::: "memory"); }

// ============================================================================
// prep kernels
// ============================================================================
__global__ __launch_bounds__(256) void k_init(u64* __restrict__ rowmin,
                                              int* __restrict__ counts) {
  int i = blockIdx.x * 256 + threadIdx.x;
  rowmin[i] = ~0ull;
  if (i < KC) counts[i] = 0;
}

__global__ __launch_bounds__(256) void k_prept(const float* __restrict__ W,
                                               f16* __restrict__ o1,
                                               f16* __restrict__ o2,
                                               int K, int N) {
  __shared__ float tile[32][33];
  int tx = threadIdx.x & 31, ty = threadIdx.x >> 5;
  int nb = blockIdx.x * 32, kb = blockIdx.y * 32;
#pragma unroll
  for (int i = 0; i < 32; i += 8)
    tile[ty + i][tx] = W[(size_t)(kb + ty + i) * N + nb + tx];
  __syncthreads();
#pragma unroll
  for (int i = 0; i < 32; i += 8) {
    float v = tile[tx][ty + i];
    f16 h = (f16)v;
    size_t o = (size_t)(nb + ty + i) * K + kb + tx;
    o1[o] = h;
    if (o2) o2[o] = (f16)((v - (float)h) * SPLIT_SC);
  }
}

__global__ __launch_bounds__(256) void k_prepe(const float* __restrict__ E,
                                               f16* __restrict__ e1,
                                               f16* __restrict__ e2) {
  int tid = blockIdx.x * 256 + threadIdx.x;
  for (int i = tid; i < KC * DM; i += 131072) {
    float v = E[i];
    f16 h = (f16)v;
    e1[i] = h;
    e2[i] = (f16)((v - (float)h) * SPLIT_SC);
  }
}

__global__ __launch_bounds__(64) void k_enorm(const float* __restrict__ E,
                                              float* __restrict__ enorm) {
  int k = blockIdx.x, t = threadIdx.x;
  float s = 0.f;
#pragma unroll
  for (int j = 0; j < 8; j++) {
    float v = E[(size_t)k * DM + t + j * 64];
    s = fmaf(v, v, s);
  }
#pragma unroll
  for (int m = 1; m < 64; m <<= 1) s += __shfl_xor(s, m, 64);
  if (t == 0) enorm[k] = s;
}

// ============================================================================
// encoder GEMM: 128x128 tile, BK=32, B via gload_lds dbuf, A reg-staged
// ============================================================================
__global__ __launch_bounds__(512) void k_genc2(const float* __restrict__ x,
                                               const f16* __restrict__ wt1,
                                               const f16* __restrict__ wt2,
                                               const float* __restrict__ bias,
                                               float* __restrict__ dst) {
  __shared__ __align__(16) f16 A1[128 * 32], A2[128 * 32];
  __shared__ __align__(16) f16 B1[2][128 * 32], B2[2][128 * 32];
  int t = threadIdx.x, lane = t & 63, wid = t >> 6;
  int wm = wid >> 2, wn = wid & 3;
  int l = blockIdx.x;
  int xcd = l & 7, s = l >> 3, ct = s & 3;
  int p = ((s >> 2) << 3) | xcd;
  int m0 = p * 128, n0 = ct * 128;
  int r = t >> 2, cg = t & 3;
  int cslot = cg ^ ((r >> 1) & 3);
  const float* ax = x + (size_t)(m0 + r) * DIN + cg * 8;
  f32x4 accA[4][2] = {}, accB[4][2] = {};

  float4 av0 = *(const float4*)(ax);
  float4 av1 = *(const float4*)(ax + 4);
  stage32(wt1, DIN, n0, 0, B1[0], t);
  stage32(wt2, DIN, n0, 0, B2[0], t);
  int cur = 0;

  for (int it = 0; it < 32; ++it) {
    float4 nv0 = av0, nv1 = av1;
    if (it < 31) {
      int k0n = (it + 1) * 32;
      stage32(wt1, DIN, n0, k0n, B1[cur ^ 1], t);
      stage32(wt2, DIN, n0, k0n, B2[cur ^ 1], t);
      nv0 = *(const float4*)(ax + k0n);
      nv1 = *(const float4*)(ax + k0n + 4);
      asm volatile("s_waitcnt vmcnt(4)" ::: "memory");
    } else {
      asm volatile("s_waitcnt vmcnt(0)" ::: "memory");
    }
    {
      float a[8] = {av0.x, av0.y, av0.z, av0.w, av1.x, av1.y, av1.z, av1.w};
      f16 h1[8], h2[8];
#pragma unroll
      for (int j = 0; j < 8; j++) {
        f16 h = (f16)a[j];
        h1[j] = h;
        h2[j] = (f16)((a[j] - (float)h) * SPLIT_SC);
      }
      *(f16x8*)(A1 + r * 32 + cslot * 8) = *(f16x8*)h1;
      *(f16x8*)(A2 + r * 32 + cslot * 8) = *(f16x8*)h2;
    }
    asm volatile("s_waitcnt lgkmcnt(0)" ::: "memory");
    __builtin_amdgcn_sched_barrier(0);
    __builtin_amdgcn_s_barrier();
    asm volatile("" ::: "memory");
    {
      int kc = lane >> 4;
      f16x8 a1f[4], a2f[4], b1f[2], b2f[2];
#pragma unroll
      for (int m = 0; m < 4; m++) {
        int row = wm * 64 + m * 16 + (lane & 15);
        a1f[m] = ldfrag32(A1, row, kc);
        a2f[m] = ldfrag32(A2, row, kc);
      }
#pragma unroll
      for (int n = 0; n < 2; n++) {
        int row = wn * 32 + n * 16 + (lane & 15);
        b1f[n] = ldfrag32(B1[cur], row, kc);
        b2f[n] = ldfrag32(B2[cur], row, kc);
      }
#pragma unroll
      for (int m = 0; m < 4; m++)
#pragma unroll
        for (int n = 0; n < 2; n++) {
          accA[m][n] = MFMA16(a1f[m], b1f[n], accA[m][n]);
          accB[m][n] = MFMA16(a1f[m], b2f[n], accB[m][n]);
          accB[m][n] = MFMA16(a2f[m], b1f[n], accB[m][n]);
        }
    }
    BAR2;
    av0 = nv0; av1 = nv1; cur ^= 1;
  }
#pragma unroll
  for (int m = 0; m < 4; m++)
#pragma unroll
    for (int n = 0; n < 2; n++)
#pragma unroll
      for (int j = 0; j < 4; j++) {
        int row = m0 + wm * 64 + m * 16 + (lane >> 4) * 4 + j;
        int col = n0 + wn * 32 + n * 16 + (lane & 15);
        dst[(size_t)row * DM + col] = accA[m][n][j] + SPLIT_INV * accB[m][n][j] + bias[col];
      }
}

// ============================================================================
// distance GEMM + argmin: 2048 blocks, BK=32, gload_lds dbuf, global atomicMin
// ============================================================================
__global__ __launch_bounds__(512) void k_dist2(const f16* __restrict__ z1,
                                               const f16* __restrict__ z2,
                                               const f16* __restrict__ e1,
                                               const f16* __restrict__ e2,
                                               const float* __restrict__ enorm,
                                               u64* __restrict__ rowmin) {
  __shared__ __align__(16) f16 A1[2][128 * 32], A2[2][128 * 32];
  __shared__ __align__(16) f16 B1[2][128 * 32], B2[2][128 * 32];
  int t = threadIdx.x, lane = t & 63, wid = t >> 6;
  int wm = wid >> 2, wn = wid & 3;
  int l = blockIdx.x;
  int xcd = l & 7, s = l >> 3, ct = s & 7;
  int p = ((s >> 3) << 3) | xcd;
  int r0 = p * 128, c0 = ct * 128;
  f32x4 accA[4][2] = {}, accB[4][2] = {};

  stage32(z1, DM, r0, 0, A1[0], t);
  stage32(z2, DM, r0, 0, A2[0], t);
  stage32(e1, DM, c0, 0, B1[0], t);
  stage32(e2, DM, c0, 0, B2[0], t);
  int cur = 0;

  for (int it = 0; it < 16; ++it) {
    if (it < 15) {
      int k0n = (it + 1) * 32;
      stage32(z1, DM, r0, k0n, A1[cur ^ 1], t);
      stage32(z2, DM, r0, k0n, A2[cur ^ 1], t);
      stage32(e1, DM, c0, k0n, B1[cur ^ 1], t);
      stage32(e2, DM, c0, k0n, B2[cur ^ 1], t);
      BAR1_V4;
    } else {
      BAR1_V0L0;
    }
    {
      int kc = lane >> 4;
      f16x8 a1f[4], a2f[4], b1f[2], b2f[2];
#pragma unroll
      for (int m = 0; m < 4; m++) {
        int row = wm * 64 + m * 16 + (lane & 15);
        a1f[m] = ldfrag32(A1[cur], row, kc);
        a2f[m] = ldfrag32(A2[cur], row, kc);
      }
#pragma unroll
      for (int n = 0; n < 2; n++) {
        int row = wn * 32 + n * 16 + (lane & 15);
        b1f[n] = ldfrag32(B1[cur], row, kc);
        b2f[n] = ldfrag32(B2[cur], row, kc);
      }
#pragma unroll
      for (int m = 0; m < 4; m++)
#pragma unroll
        for (int n = 0; n < 2; n++) {
          accA[m][n] = MFMA16(a1f[m], b1f[n], accA[m][n]);
          accB[m][n] = MFMA16(a1f[m], b2f[n], accB[m][n]);
          accB[m][n] = MFMA16(a2f[m], b1f[n], accB[m][n]);
        }
    }
    BAR2;
    cur ^= 1;
  }

  float en0 = enorm[c0 + wn * 32 + (lane & 15)];
  float en1 = enorm[c0 + wn * 32 + 16 + (lane & 15)];
#pragma unroll
  for (int m = 0; m < 4; m++)
#pragma unroll
    for (int j = 0; j < 4; j++) {
      int r_l = wm * 64 + m * 16 + (lane >> 4) * 4 + j;
      u64 best = ~0ull;
#pragma unroll
      for (int n = 0; n < 2; n++) {
        int col = c0 + wn * 32 + n * 16 + (lane & 15);
        float dot = accA[m][n][j] + SPLIT_INV * accB[m][n][j];
        float sc = fmaf(-2.0f, dot, n ? en1 : en0);
        u32 kb = __float_as_uint(sc);
        kb = (kb & 0x80000000u) ? ~kb : (kb | 0x80000000u);
        u64 pk = ((u64)kb << 32) | (u32)col;
        best = pk < best ? pk : best;
      }
#pragma unroll
      for (int msk = 1; msk < 16; msk <<= 1) {
        u64 o = __shfl_xor(best, msk, 64);
        best = o < best ? o : best;
      }
      if ((lane & 15) == 0) atomicMin(rowmin + r0 + r_l, best);
    }
}

// ============================================================================
// decoder GEMM: BK=64, all-f16 gload_lds dbuf, 2048 blocks XCD-swizzled
// ============================================================================
__global__ __launch_bounds__(512) void k_gdec2(const f16* __restrict__ zq16,
                                               const f16* __restrict__ dT,
                                               const float* __restrict__ bias,
                                               float* __restrict__ dst) {
  __shared__ __align__(16) f16 A1[2][128 * 64], B1[2][128 * 64];
  int t = threadIdx.x, lane = t & 63, wid = t >> 6;
  int wm = wid >> 2, wn = wid & 3;
  int l = blockIdx.x;
  int xcd = l & 7, s = l >> 3, ct = s & 7;
  int p = ((s >> 3) << 3) | xcd;
  int m0 = p * 128, n0 = ct * 128;
  f32x4 acc[4][2] = {};

  stage64(zq16, DM, m0, 0, A1[0], t);
  stage64(dT, DM, n0, 0, B1[0], t);
  int cur = 0;

  for (int it = 0; it < 8; ++it) {
    if (it < 7) {
      int k0n = (it + 1) * 64;
      stage64(zq16, DM, m0, k0n, A1[cur ^ 1], t);
      stage64(dT, DM, n0, k0n, B1[cur ^ 1], t);
      BAR1_V4;
    } else {
      BAR1_V0L0;
    }
#pragma unroll
    for (int kk = 0; kk < 2; kk++) {
      int kc = kk * 4 + (lane >> 4);
      f16x8 a1f[4], b1f[2];
#pragma unroll
      for (int m = 0; m < 4; m++)
        a1f[m] = ldfrag64(A1[cur], wm * 64 + m * 16 + (lane & 15), kc);
#pragma unroll
      for (int n = 0; n < 2; n++)
        b1f[n] = ldfrag64(B1[cur], wn * 32 + n * 16 + (lane & 15), kc);
#pragma unroll
      for (int m = 0; m < 4; m++)
#pragma unroll
        for (int n = 0; n < 2; n++) acc[m][n] = MFMA16(a1f[m], b1f[n], acc[m][n]);
    }
    BAR2;
    cur ^= 1;
  }
#pragma unroll
  for (int m = 0; m < 4; m++)
#pragma unroll
    for (int n = 0; n < 2; n++)
#pragma unroll
      for (int j = 0; j < 4; j++) {
        int row = m0 + wm * 64 + m * 16 + (lane >> 4) * 4 + j;
        int col = n0 + wn * 32 + n * 16 + (lane & 15);
        dst[(size_t)row * DIN + col] = acc[m][n][j] + bias[col];
      }
}

// ============================================================================
// gather v2: 2048 blocks x 256 thr, 16 rows/block. No same-address atomics:
// commit-loss goes to a per-block partial, reduced deterministically in k_scan.
// ============================================================================
__global__ __launch_bounds__(256) void k_gather2(const u64* __restrict__ rowmin,
                                                 const float* __restrict__ E,
                                                 float* __restrict__ out,
                                                 int* __restrict__ idxws,
                                                 int* __restrict__ counts,
                                                 float* __restrict__ cpart,
                                                 f16* __restrict__ zq16) {
  int t = threadIdx.x;
  int r0 = blockIdx.x * GROWS;
  __shared__ int idx_s[GROWS];
  if (t < GROWS) {
    int R = r0 + t;
    int idx = (int)(u32)(rowmin[R] & 0xffffffffull);
    idx_s[t] = idx;
    out[OFF_IDX + R] = (float)idx;
    idxws[R] = idx;
    atomicAdd(counts + idx, 1);
  }
  __syncthreads();
  float loc = 0.f;
  for (int r = 0; r < GROWS; r++) {
    int R = r0 + r;
    const float* e = E + (size_t)idx_s[r] * DM;
    const float* z = out + OFF_ZE + (size_t)R * DM;
    float* zq = out + OFF_ZQ + (size_t)R * DM;
    f16* zp = zq16 + (size_t)R * DM;
#pragma unroll
    for (int j = 0; j < 2; j++) {
      int c = t + j * 256;
      float q = e[c];
      float zz = z[c];
      zq[c] = q;
      zp[c] = (f16)q;
      float d = zz - q;
      loc = fmaf(d, d, loc);
    }
  }
#pragma unroll
  for (int m = 1; m < 64; m <<= 1) loc += __shfl_xor(loc, m, 64);
  __shared__ float sh[4];
  if ((t & 63) == 0) sh[t >> 6] = loc;
  __syncthreads();
  if (t == 0) cpart[blockIdx.x] = sh[0] + sh[1] + sh[2] + sh[3];
}

// ============================================================================
// LayerNorm + f16 split planes of z_e
// ============================================================================
__global__ __launch_bounds__(256) void k_ln2(float* __restrict__ ze,
                                             const float* __restrict__ g,
                                             const float* __restrict__ b,
                                             f16* __restrict__ z1,
                                             f16* __restrict__ z2) {
  int t = threadIdx.x, lane = t & 63, wid = t >> 6;
  int R = blockIdx.x * 4 + wid;
  float* row = ze + (size_t)R * DM;
  float v[8];
  float s = 0.f, sq = 0.f;
#pragma unroll
  for (int j = 0; j < 8; j++) {
    v[j] = row[lane + j * 64];
    s += v[j];
    sq = fmaf(v[j], v[j], sq);
  }
#pragma unroll
  for (int m = 1; m < 64; m <<= 1) {
    s += __shfl_xor(s, m, 64);
    sq += __shfl_xor(sq, m, 64);
  }
  float mu = s * (1.f / DM);
  float var = sq * (1.f / DM) - mu * mu;
  float rs = rsqrtf(var + 1e-5f);
#pragma unroll
  for (int j = 0; j < 8; j++) {
    int c = lane + j * 64;
    float o = (v[j] - mu) * rs * g[c] + b[c];
    row[c] = o;
    f16 h = (f16)o;
    z1[(size_t)R * DM + c] = h;
    z2[(size_t)R * DM + c] = (f16)((o - (float)h) * SPLIT_SC);
  }
}

// ============================================================================
// EMA tail: scan (+ deterministic commit reduce) + chunked segment-sum
// ============================================================================
__global__ __launch_bounds__(1024) void k_scan(const int* __restrict__ counts,
                                               const float* __restrict__ cs_in,
                                               float* __restrict__ out,
                                               int* __restrict__ starts,
                                               int* __restrict__ offw,
                                               float* __restrict__ csd,
                                               const float* __restrict__ cpart,
                                               int* __restrict__ chpfx,
                                               int* __restrict__ chcode) {
  __shared__ float f[1024];
  __shared__ int ib[1024];
  int t = threadIdx.x;
  // deterministic commit-loss reduction over 2048 block partials
  f[t] = cpart[t] + cpart[t + 1024];
  __syncthreads();
  for (int s = 512; s > 0; s >>= 1) {
    if (t < s) f[t] += f[t + s];
    __syncthreads();
  }
  if (t == 0) out[OFF_CL] = f[0] * (1.f / ((float)NROWS * (float)DM));
  __syncthreads();

  int cnt = counts[t];
  float ncs = 0.99f * cs_in[t] + 0.01f * (float)cnt;
  out[OFF_NCS + t] = ncs;
  f[t] = ncs;
  __syncthreads();
  for (int s = 512; s > 0; s >>= 1) {
    if (t < s) f[t] += f[t + s];
    __syncthreads();
  }
  float n = f[0];
  csd[t] = (ncs + 1e-5f) / (n + (float)KC * 1e-5f) * n;
  ib[t] = cnt;
  __syncthreads();
  for (int s = 1; s < 1024; s <<= 1) {
    int y = (t >= s) ? ib[t - s] : 0;
    __syncthreads();
    ib[t] += y;
    __syncthreads();
  }
  int excl = ib[t] - cnt;
  starts[t] = excl;
  offw[t] = excl;
  int nch = (cnt + CHSZ - 1) / CHSZ;
  __syncthreads();
  ib[t] = nch;
  __syncthreads();
  for (int s = 1; s < 1024; s <<= 1) {
    int y = (t >= s) ? ib[t - s] : 0;
    __syncthreads();
    ib[t] += y;
    __syncthreads();
  }
  int chx = ib[t] - nch;
  chpfx[t] = chx;
  if (t == KC - 1) chpfx[KC] = ib[t];
  for (int j = 0; j < nch; j++) chcode[chx + j] = t;
}

__global__ __launch_bounds__(256) void k_scatter(const int* __restrict__ idxws,
                                                 int* __restrict__ offw,
                                                 int* __restrict__ rowlist) {
  int r = blockIdx.x * 256 + threadIdx.x;
  int idx = idxws[r];
  int pos = atomicAdd(offw + idx, 1);
  rowlist[pos] = r;
}

__global__ __launch_bounds__(128) void k_partsum(const int* __restrict__ chpfx,
                                                 const int* __restrict__ chcode,
                                                 const int* __restrict__ starts,
                                                 const int* __restrict__ counts,
                                                 const int* __restrict__ rowlist,
                                                 const float* __restrict__ out,
                                                 float* __restrict__ part) {
  int c = blockIdx.x, t = threadIdx.x;
  if (c >= chpfx[KC]) return;
  int code = chcode[c];
  int j = c - chpfx[code];
  int ofs = starts[code] + j * CHSZ;
  int len = min(CHSZ, counts[code] - j * CHSZ);
  __shared__ int rl[CHSZ];
  if (t < len) rl[t] = rowlist[ofs + t];
  __syncthreads();
  const float* zeb = out + OFF_ZE;
  float a0 = 0.f, a1 = 0.f, a2 = 0.f, a3 = 0.f;
  for (int i = 0; i < len; i++) {
    const float* z = zeb + (size_t)rl[i] * DM;
    a0 += z[t];
    a1 += z[t + 128];
    a2 += z[t + 256];
    a3 += z[t + 384];
  }
  float* pp = part + (size_t)c * DM;
  pp[t] = a0;
  pp[t + 128] = a1;
  pp[t + 256] = a2;
  pp[t + 384] = a3;
}

__global__ __launch_bounds__(128) void k_codesum2(const int* __restrict__ chpfx,
                                                  const float* __restrict__ part,
                                                  const float* __restrict__ ema_in,
                                                  const float* __restrict__ csd,
                                                  float* __restrict__ out) {
  int k = blockIdx.x, t = threadIdx.x;
  int base = chpfx[k], nch = chpfx[k + 1] - base;
  float a0 = 0.f, a1 = 0.f, a2 = 0.f, a3 = 0.f;
  for (int i = 0; i < nch; i++) {
    const float* pp = part + (size_t)(base + i) * DM;
    a0 += pp[t];
    a1 += pp[t + 128];
    a2 += pp[t + 256];
    a3 += pp[t + 384];
  }
  float cs = csd[k];
  float sum[4] = {a0, a1, a2, a3};
#pragma unroll
  for (int j = 0; j < 4; j++) {
    int c = t + j * 128;
    float e = 0.99f * ema_in[(size_t)k * DM + c] + 0.01f * sum[j];
    out[OFF_NEMA + (size_t)k * DM + c] = e;
    out[OFF_NE + (size_t)k * DM + c] = e / cs;
  }
}

// ============================================================================
extern "C" void kernel_launch(void* const* d_in, const int* in_sizes, int n_in,
                              void* d_out, int out_size, void* d_ws, size_t ws_size,
                              hipStream_t stream) {
  (void)in_sizes; (void)n_in; (void)out_size; (void)ws_size;
  const float* x = (const float*)d_in[0];
  const float* enc_w = (const float*)d_in[1];
  const float* enc_b = (const float*)d_in[2];
  const float* ln_g = (const float*)d_in[3];
  const float* ln_b = (const float*)d_in[4];
  const float* dec_w = (const float*)d_in[5];
  const float* dec_b = (const float*)d_in[6];
  const float* emb = (const float*)d_in[7];
  const float* cs_in = (const float*)d_in[8];
  const float* ema_in = (const float*)d_in[9];
  float* out = (float*)d_out;
  char* ws = (char*)d_ws;
  u64* rowmin = (u64*)(ws + WS_ROWMIN);
  int* idxws = (int*)(ws + WS_IDX);
  int* counts = (int*)(ws + WS_COUNTS);
  int* starts = (int*)(ws + WS_STARTS);
  int* offw = (int*)(ws + WS_OFFW);
  int* rowlist = (int*)(ws + WS_ROWLIST);
  float* csd = (float*)(ws + WS_CSD);
  float* enorm = (float*)(ws + WS_ENORM);
  f16* zq16 = (f16*)(ws + WS2_ZQ16);
  f16* wt1 = (f16*)(ws + WS2_WT1);
  f16* wt2 = (f16*)(ws + WS2_WT2);
  f16* dT = (f16*)(ws + WS2_DT);
  f16* e1 = (f16*)(ws + WS2_E1);
  f16* e2 = (f16*)(ws + WS2_E2);
  int* chpfx = (int*)(ws + WS3_CHPFX);
  int* chcode = (int*)(ws + WS3_CHCODE);
  float* cpart = (float*)(ws + WS3_CPART);
  float* part = (float*)(ws + WS3_PART);
  f16* z1 = (f16*)out;                 // scratch in x_recon region (overwritten by k_gdec2)
  f16* z2 = z1 + (size_t)NROWS * DM;

  k_init<<<dim3(NROWS / 256), dim3(256), 0, stream>>>(rowmin, counts);
  k_prept<<<dim3(16, 32), dim3(256), 0, stream>>>(enc_w, wt1, wt2, DIN, DM);
  k_prept<<<dim3(32, 16), dim3(256), 0, stream>>>(dec_w, dT, nullptr, DM, DIN);
  k_prepe<<<dim3(512), dim3(256), 0, stream>>>(emb, e1, e2);
  k_enorm<<<dim3(KC), dim3(64), 0, stream>>>(emb, enorm);
  k_genc2<<<dim3(1024), dim3(512), 0, stream>>>(x, wt1, wt2, enc_b, out + OFF_ZE);
  k_ln2<<<dim3(8192), dim3(256), 0, stream>>>(out + OFF_ZE, ln_g, ln_b, z1, z2);
  k_dist2<<<dim3(2048), dim3(512), 0, stream>>>(z1, z2, e1, e2, enorm, rowmin);
  k_gather2<<<dim3(NROWS / GROWS), dim3(256), 0, stream>>>(rowmin, emb, out, idxws,
                                                           counts, cpart, zq16);
  k_scan<<<dim3(1), dim3(1024), 0, stream>>>(counts, cs_in, out, starts, offw, csd,
                                             cpart, chpfx, chcode);
  k_scatter<<<dim3(NROWS / 256), dim3(256), 0, stream>>>(idxws, offw, rowlist);
  k_partsum<<<dim3(MAXCH), dim3(128), 0, stream>>>(chpfx, chcode, starts, counts,
                                                   rowlist, out, part);
  k_codesum2<<<dim3(KC), dim3(128), 0, stream>>>(chpfx, part, ema_in, csd, out);
  k_gdec2<<<dim3(2048), dim3(512), 0, stream>>>(zq16, dT, dec_b, out + OFF_XR);
}

// Round 6
// 388.754 us; speedup vs baseline: 2.1174x; 1.1437x over previous
//
#include <hip/hip_runtime.h>

typedef unsigned long long u64;
typedef unsigned int u32;
typedef _Float16 f16;
typedef _Float16 f16x8 __attribute__((ext_vector_type(8)));
typedef float f32x4 __attribute__((ext_vector_type(4)));

#define MFMA16(a, b, c) __builtin_amdgcn_mfma_f32_16x16x32_f16(a, b, c, 0, 0, 0)

#define NROWS 32768
#define DIN   1024
#define DM    512
#define KC    1024
#define SPLIT_SC  1024.0f
#define SPLIT_INV 0.0009765625f
#define CHSZ  32
#define MAXCH 2048
#define MARGIN 0.5f

// ---- output float offsets ----
#define OFF_XR   0ull
#define OFF_CL   33554432ull
#define OFF_IDX  33554433ull
#define OFF_ZE   33587201ull   // base %4==1 -> scalar access only
#define OFF_ZQ   50364417ull
#define OFF_NE   67141633ull
#define OFF_NCS  67665921ull
#define OFF_NEMA 67666945ull

// ---- workspace byte offsets ----
#define WS_ZNORM   2359296ull  // float[32768]
#define WS_IDX     2490368ull
#define WS_COUNTS  2621440ull
#define WS_STARTS  2625536ull
#define WS_OFFW    2629632ull
#define WS_ROWLIST 2633728ull
#define WS_CSD     2764800ull
#define WS_ENORM   2769920ull
#define WS2_CAND   (4ull<<20)   // u64[32768*16] = 4MB  per-(row,tile) top-2 keys
#define WS2_WT1    (36ull<<20)
#define WS2_WT2    (37ull<<20)
#define WS2_DT     (38ull<<20)
#define WS2_E1     (39ull<<20)
#define WS3_CHPFX  (41ull<<20)
#define WS3_CHCODE ((41ull<<20) + 8192)
#define WS3_CPART  ((41ull<<20) + 16384)   // float[2048]
#define WS3_PART   ((41ull<<20) + 65536)

// ============================================================================
// LDS helpers (proven rounds 4-5 patterns)
// ============================================================================
__device__ inline void gload16(const f16* g, f16* l) {
  __builtin_amdgcn_global_load_lds((const __attribute__((address_space(1))) void*)g,
                                   (__attribute__((address_space(3))) void*)l, 16, 0, 0);
}

__device__ inline f16x8 ldfrag32(const f16* p, int row, int kc) {
  return *(const f16x8*)(p + row * 32 + ((kc ^ ((row >> 1) & 3)) << 3));
}
__device__ inline f16x8 ldfrag64(const f16* p, int row, int kc) {
  return *(const f16x8*)(p + row * 64 + ((kc ^ (row & 7)) << 3));
}

__device__ inline void stage32(const f16* gbase, int ld, int row0, int k0,
                               f16* lds, int t) {
  int r = t >> 2, c = t & 3;
  int cs = c ^ ((r >> 1) & 3);
  gload16(gbase + (size_t)(row0 + r) * ld + k0 + cs * 8, lds + t * 8);
}

__device__ inline void stage64(const f16* gbase, int ld, int row0, int k0,
                               f16* lds, int t) {
#pragma unroll
  for (int h = 0; h < 2; h++) {
    int e = t + h * 512;
    int r = e >> 3, c = e & 7;
    int cs = c ^ (r & 7);
    gload16(gbase + (size_t)(row0 + r) * ld + k0 + cs * 8, lds + e * 8);
  }
}

#define BAR1_V4   { asm volatile("s_waitcnt vmcnt(4)" ::: "memory"); \
                    __builtin_amdgcn_sched_barrier(0); \
                    __builtin_amdgcn_s_barrier(); \
                    asm volatile("" ::: "memory"); }
#define BAR1_V0L0 { asm volatile("s_waitcnt vmcnt(0) lgkmcnt(0)" ::: "memory"); \
                    __builtin_amdgcn_sched_barrier(0); \
                    __builtin_amdgcn_s_barrier(); \
                    asm volatile("" ::: "memory"); }
#define BAR2      { asm volatile("s_waitcnt lgkmcnt(0)" ::: "memory"); \
                    __builtin_amdgcn_s_barrier(); \
                    asm volatile("" ::: "memory"); }

// monotone float->u32 map and inverse (argmin packing)
__device__ inline u32 enc_score(float s) {
  u32 kb = __float_as_uint(s);
  return (kb & 0x80000000u) ? ~kb : (kb | 0x80000000u);
}
__device__ inline float dec_score(u32 u) {
  u32 b = (u & 0x80000000u) ? (u & 0x7fffffffu) : ~u;
  return __uint_as_float(b);
}

// ============================================================================
// prep kernels
// ============================================================================
__global__ __launch_bounds__(256) void k_init(int* __restrict__ counts) {
  int i = blockIdx.x * 256 + threadIdx.x;
  if (i < KC) counts[i] = 0;
}

__global__ __launch_bounds__(256) void k_prept(const float* __restrict__ W,
                                               f16* __restrict__ o1,
                                               f16* __restrict__ o2,
                                               int K, int N) {
  __shared__ float tile[32][33];
  int tx = threadIdx.x & 31, ty = threadIdx.x >> 5;
  int nb = blockIdx.x * 32, kb = blockIdx.y * 32;
#pragma unroll
  for (int i = 0; i < 32; i += 8)
    tile[ty + i][tx] = W[(size_t)(kb + ty + i) * N + nb + tx];
  __syncthreads();
#pragma unroll
  for (int i = 0; i < 32; i += 8) {
    float v = tile[tx][ty + i];
    f16 h = (f16)v;
    size_t o = (size_t)(nb + ty + i) * K + kb + tx;
    o1[o] = h;
    if (o2) o2[o] = (f16)((v - (float)h) * SPLIT_SC);
  }
}

__global__ __launch_bounds__(256) void k_prepe(const float* __restrict__ E,
                                               f16* __restrict__ e1) {
  int tid = blockIdx.x * 256 + threadIdx.x;
  for (int i = tid; i < KC * DM; i += 131072) e1[i] = (f16)E[i];
}

__global__ __launch_bounds__(64) void k_enorm(const float* __restrict__ E,
                                              float* __restrict__ enorm) {
  int k = blockIdx.x, t = threadIdx.x;
  float s = 0.f;
#pragma unroll
  for (int j = 0; j < 8; j++) {
    float v = E[(size_t)k * DM + t + j * 64];
    s = fmaf(v, v, s);
  }
#pragma unroll
  for (int m = 1; m < 64; m <<= 1) s += __shfl_xor(s, m, 64);
  if (t == 0) enorm[k] = s;
}

// ============================================================================
// encoder GEMM (unchanged, proven): 128x128, BK=32, split-f16 3-product
// ============================================================================
__global__ __launch_bounds__(512) void k_genc2(const float* __restrict__ x,
                                               const f16* __restrict__ wt1,
                                               const f16* __restrict__ wt2,
                                               const float* __restrict__ bias,
                                               float* __restrict__ dst) {
  __shared__ __align__(16) f16 A1[128 * 32], A2[128 * 32];
  __shared__ __align__(16) f16 B1[2][128 * 32], B2[2][128 * 32];
  int t = threadIdx.x, lane = t & 63, wid = t >> 6;
  int wm = wid >> 2, wn = wid & 3;
  int l = blockIdx.x;
  int xcd = l & 7, s = l >> 3, ct = s & 3;
  int p = ((s >> 2) << 3) | xcd;
  int m0 = p * 128, n0 = ct * 128;
  int r = t >> 2, cg = t & 3;
  int cslot = cg ^ ((r >> 1) & 3);
  const float* ax = x + (size_t)(m0 + r) * DIN + cg * 8;
  f32x4 accA[4][2] = {}, accB[4][2] = {};

  float4 av0 = *(const float4*)(ax);
  float4 av1 = *(const float4*)(ax + 4);
  stage32(wt1, DIN, n0, 0, B1[0], t);
  stage32(wt2, DIN, n0, 0, B2[0], t);
  int cur = 0;

  for (int it = 0; it < 32; ++it) {
    float4 nv0 = av0, nv1 = av1;
    if (it < 31) {
      int k0n = (it + 1) * 32;
      stage32(wt1, DIN, n0, k0n, B1[cur ^ 1], t);
      stage32(wt2, DIN, n0, k0n, B2[cur ^ 1], t);
      nv0 = *(const float4*)(ax + k0n);
      nv1 = *(const float4*)(ax + k0n + 4);
      asm volatile("s_waitcnt vmcnt(4)" ::: "memory");
    } else {
      asm volatile("s_waitcnt vmcnt(0)" ::: "memory");
    }
    {
      float a[8] = {av0.x, av0.y, av0.z, av0.w, av1.x, av1.y, av1.z, av1.w};
      f16 h1[8], h2[8];
#pragma unroll
      for (int j = 0; j < 8; j++) {
        f16 h = (f16)a[j];
        h1[j] = h;
        h2[j] = (f16)((a[j] - (float)h) * SPLIT_SC);
      }
      *(f16x8*)(A1 + r * 32 + cslot * 8) = *(f16x8*)h1;
      *(f16x8*)(A2 + r * 32 + cslot * 8) = *(f16x8*)h2;
    }
    asm volatile("s_waitcnt lgkmcnt(0)" ::: "memory");
    __builtin_amdgcn_sched_barrier(0);
    __builtin_amdgcn_s_barrier();
    asm volatile("" ::: "memory");
    {
      int kc = lane >> 4;
      f16x8 a1f[4], a2f[4], b1f[2], b2f[2];
#pragma unroll
      for (int m = 0; m < 4; m++) {
        int row = wm * 64 + m * 16 + (lane & 15);
        a1f[m] = ldfrag32(A1, row, kc);
        a2f[m] = ldfrag32(A2, row, kc);
      }
#pragma unroll
      for (int n = 0; n < 2; n++) {
        int row = wn * 32 + n * 16 + (lane & 15);
        b1f[n] = ldfrag32(B1[cur], row, kc);
        b2f[n] = ldfrag32(B2[cur], row, kc);
      }
#pragma unroll
      for (int m = 0; m < 4; m++)
#pragma unroll
        for (int n = 0; n < 2; n++) {
          accA[m][n] = MFMA16(a1f[m], b1f[n], accA[m][n]);
          accB[m][n] = MFMA16(a1f[m], b2f[n], accB[m][n]);
          accB[m][n] = MFMA16(a2f[m], b1f[n], accB[m][n]);
        }
    }
    BAR2;
    av0 = nv0; av1 = nv1; cur ^= 1;
  }
#pragma unroll
  for (int m = 0; m < 4; m++)
#pragma unroll
    for (int n = 0; n < 2; n++)
#pragma unroll
      for (int j = 0; j < 4; j++) {
        int row = m0 + wm * 64 + m * 16 + (lane >> 4) * 4 + j;
        int col = n0 + wn * 32 + n * 16 + (lane & 15);
        dst[(size_t)row * DM + col] = accA[m][n][j] + SPLIT_INV * accB[m][n][j] + bias[col];
      }
}

// ============================================================================
// distance GEMM v3: 1-product f16, BK=64 (clone of proven gdec2 loop).
// Epilogue: per-(row, 128-col tile) TOP-2 packed keys -> cand[row][ct*2+{0,1}].
// ============================================================================
__global__ __launch_bounds__(512) void k_dist3(const f16* __restrict__ z1,
                                               const f16* __restrict__ e1,
                                               const float* __restrict__ enorm,
                                               u64* __restrict__ cand) {
  __shared__ __align__(16) f16 A1[2][128 * 64], B1[2][128 * 64];
  __shared__ u64 cand_s[128][8];
  int t = threadIdx.x, lane = t & 63, wid = t >> 6;
  int wm = wid >> 2, wn = wid & 3;
  int l = blockIdx.x;
  int xcd = l & 7, s = l >> 3, ct = s & 7;
  int p = ((s >> 3) << 3) | xcd;
  int r0 = p * 128, c0 = ct * 128;
  f32x4 acc[4][2] = {};

  stage64(z1, DM, r0, 0, A1[0], t);
  stage64(e1, DM, c0, 0, B1[0], t);
  int cur = 0;

  for (int it = 0; it < 8; ++it) {
    if (it < 7) {
      int k0n = (it + 1) * 64;
      stage64(z1, DM, r0, k0n, A1[cur ^ 1], t);
      stage64(e1, DM, c0, k0n, B1[cur ^ 1], t);
      BAR1_V4;
    } else {
      BAR1_V0L0;
    }
#pragma unroll
    for (int kk = 0; kk < 2; kk++) {
      int kc = kk * 4 + (lane >> 4);
      f16x8 a1f[4], b1f[2];
#pragma unroll
      for (int m = 0; m < 4; m++)
        a1f[m] = ldfrag64(A1[cur], wm * 64 + m * 16 + (lane & 15), kc);
#pragma unroll
      for (int n = 0; n < 2; n++)
        b1f[n] = ldfrag64(B1[cur], wn * 32 + n * 16 + (lane & 15), kc);
#pragma unroll
      for (int m = 0; m < 4; m++)
#pragma unroll
        for (int n = 0; n < 2; n++) acc[m][n] = MFMA16(a1f[m], b1f[n], acc[m][n]);
    }
    BAR2;
    cur ^= 1;
  }

  // epilogue: approx scores -> per-row top-2 within this 128-col tile
  float en0 = enorm[c0 + wn * 32 + (lane & 15)];
  float en1 = enorm[c0 + wn * 32 + 16 + (lane & 15)];
#pragma unroll
  for (int m = 0; m < 4; m++)
#pragma unroll
    for (int j = 0; j < 4; j++) {
      int r_l = wm * 64 + m * 16 + (lane >> 4) * 4 + j;
      int col0 = c0 + wn * 32 + (lane & 15);
      float s0 = fmaf(-2.0f, acc[m][0][j], en0);
      float s1 = fmaf(-2.0f, acc[m][1][j], en1);
      u64 k0 = ((u64)enc_score(s0) << 32) | (u32)col0;
      u64 k1 = ((u64)enc_score(s1) << 32) | (u32)(col0 + 16);
      u64 lo = k0 < k1 ? k0 : k1;
      u64 hi = k0 < k1 ? k1 : k0;
#pragma unroll
      for (int msk = 1; msk < 16; msk <<= 1) {
        u64 lo2 = __shfl_xor(lo, msk, 64);
        u64 hi2 = __shfl_xor(hi, msk, 64);
        u64 nlo = lo < lo2 ? lo : lo2;
        u64 losr = lo < lo2 ? lo2 : lo;           // loser of lo-compare
        u64 nh = hi < hi2 ? hi : hi2;
        hi = losr < nh ? losr : nh;
        lo = nlo;
      }
      if ((lane & 15) == 0) {
        cand_s[r_l][wn * 2] = lo;
        cand_s[r_l][wn * 2 + 1] = hi;
      }
    }
  __syncthreads();
  if (t < 128) {
    u64 b0 = ~0ull, b1 = ~0ull;                    // block-wide top2 over 8 keys
#pragma unroll
    for (int i = 0; i < 8; i++) {
      u64 k = cand_s[t][i];
      if (k < b0) { b1 = b0; b0 = k; }
      else if (k < b1) { b1 = k; }
    }
    u64* dst = cand + ((size_t)(r0 + t) * 16 + ct * 2);
    dst[0] = b0;
    dst[1] = b1;
  }
}

// ============================================================================
// resolve: per row, pick argmin from 16 candidate keys; exact fp32 rescore of
// all candidates within MARGIN when >1; write idx, z_q, counts, commit partial.
// ============================================================================
__global__ __launch_bounds__(256) void k_resolve(const u64* __restrict__ cand,
                                                 const float* __restrict__ znorm,
                                                 const float* __restrict__ enorm,
                                                 const float* __restrict__ emb,
                                                 float* __restrict__ out,
                                                 int* __restrict__ idxws,
                                                 int* __restrict__ counts,
                                                 float* __restrict__ cpart) {
  int t = threadIdx.x, bid = blockIdx.x;
  int r0 = bid * 16;
  __shared__ u64 key_s[256];
  __shared__ int idx_s[16];
  __shared__ float commit_s[16];
  __shared__ int flagcnt_s;
  __shared__ int flagrow_s[16];
  key_s[t] = cand[(size_t)r0 * 16 + t];
  if (t == 0) flagcnt_s = 0;
  __syncthreads();

  if (t < 16) {
    u64 best = ~0ull;
#pragma unroll
    for (int i = 0; i < 16; i++) {
      u64 k = key_s[t * 16 + i];
      best = k < best ? k : best;
    }
    float smin = dec_score((u32)(best >> 32));
    float thr = smin + MARGIN;
    int nc = 0;
#pragma unroll
    for (int i = 0; i < 16; i++)
      if (dec_score((u32)(key_s[t * 16 + i] >> 32)) <= thr) nc++;
    idx_s[t] = (int)(u32)(best & 0xffffffffull);
    commit_s[t] = znorm[r0 + t] + smin;
    if (nc > 1) {
      int pz = atomicAdd(&flagcnt_s, 1);
      flagrow_s[pz] = t;
    }
  }
  __syncthreads();

  // exact rescore (rare): wave 0 handles flagged rows serially
  if (t < 64) {
    int nf = flagcnt_s;
    for (int fi = 0; fi < nf; fi++) {
      int lr = flagrow_s[fi];
      int R = r0 + lr;
      u64 amin = ~0ull;
      for (int i = 0; i < 16; i++) {
        u64 k = key_s[lr * 16 + i];
        amin = k < amin ? k : amin;
      }
      float thr = dec_score((u32)(amin >> 32)) + MARGIN;
      float zn = znorm[R];
      const float* z = out + OFF_ZE + (size_t)R * DM;
      u64 bestk = ~0ull;
      for (int i = 0; i < 16; i++) {
        u64 k = key_s[lr * 16 + i];
        if (dec_score((u32)(k >> 32)) > thr) continue;
        int c = (int)(u32)(k & 0xffffffffull);
        const float* e = emb + (size_t)c * DM;
        float pdot = 0.f;
#pragma unroll
        for (int j = 0; j < 8; j++) pdot = fmaf(z[t + j * 64], e[t + j * 64], pdot);
#pragma unroll
        for (int m = 1; m < 64; m <<= 1) pdot += __shfl_xor(pdot, m, 64);
        float d = fmaf(-2.0f, pdot, zn) + enorm[c];
        u64 pk = ((u64)enc_score(d) << 32) | (u32)c;
        bestk = pk < bestk ? pk : bestk;
      }
      if (t == 0) {
        idx_s[lr] = (int)(u32)(bestk & 0xffffffffull);
        commit_s[lr] = dec_score((u32)(bestk >> 32));   // exact d of winner
      }
    }
  }
  __syncthreads();

  if (t < 16) {
    int R = r0 + t;
    int idx = idx_s[t];
    out[OFF_IDX + R] = (float)idx;
    idxws[R] = idx;
    atomicAdd(counts + idx, 1);
  }
  __syncthreads();
  // gather z_q fp32
  for (int rr = 0; rr < 16; rr++) {
    int R = r0 + rr;
    const float* e = emb + (size_t)idx_s[rr] * DM;
    float* zq = out + OFF_ZQ + (size_t)R * DM;
#pragma unroll
    for (int j = 0; j < 2; j++) {
      int c = t + j * 256;
      zq[c] = e[c];
    }
  }
  if (t == 0) {
    float s = 0.f;
#pragma unroll
    for (int i = 0; i < 16; i++) s += commit_s[i];
    cpart[bid] = s;
  }
}

// ============================================================================
// decoder GEMM: A staged by GATHERING e1[idx[row]] rows (no zq16 buffer)
// ============================================================================
__global__ __launch_bounds__(512) void k_gdec3(const f16* __restrict__ e1,
                                               const int* __restrict__ idxws,
                                               const f16* __restrict__ dT,
                                               const float* __restrict__ bias,
                                               float* __restrict__ dst) {
  __shared__ __align__(16) f16 A1[2][128 * 64], B1[2][128 * 64];
  int t = threadIdx.x, lane = t & 63, wid = t >> 6;
  int wm = wid >> 2, wn = wid & 3;
  int l = blockIdx.x;
  int xcd = l & 7, s = l >> 3, ct = s & 7;
  int p = ((s >> 3) << 3) | xcd;
  int m0 = p * 128, n0 = ct * 128;
  f32x4 acc[4][2] = {};

  // per-thread fixed gather rows for A staging
  int ra = t >> 3;
  int cs = (t & 7) ^ (ra & 7);
  int ia = idxws[m0 + ra];
  int ib = idxws[m0 + 64 + ra];
  const f16* pa = e1 + (size_t)ia * DM + cs * 8;
  const f16* pb = e1 + (size_t)ib * DM + cs * 8;

  // prologue
  gload16(pa, A1[0] + t * 8);
  gload16(pb, A1[0] + (t + 512) * 8);
  stage64(dT, DM, n0, 0, B1[0], t);
  int cur = 0;

  for (int it = 0; it < 8; ++it) {
    if (it < 7) {
      int k0n = (it + 1) * 64;
      gload16(pa + k0n, A1[cur ^ 1] + t * 8);
      gload16(pb + k0n, A1[cur ^ 1] + (t + 512) * 8);
      stage64(dT, DM, n0, k0n, B1[cur ^ 1], t);
      BAR1_V4;
    } else {
      BAR1_V0L0;
    }
#pragma unroll
    for (int kk = 0; kk < 2; kk++) {
      int kc = kk * 4 + (lane >> 4);
      f16x8 a1f[4], b1f[2];
#pragma unroll
      for (int m = 0; m < 4; m++)
        a1f[m] = ldfrag64(A1[cur], wm * 64 + m * 16 + (lane & 15), kc);
#pragma unroll
      for (int n = 0; n < 2; n++)
        b1f[n] = ldfrag64(B1[cur], wn * 32 + n * 16 + (lane & 15), kc);
#pragma unroll
      for (int m = 0; m < 4; m++)
#pragma unroll
        for (int n = 0; n < 2; n++) acc[m][n] = MFMA16(a1f[m], b1f[n], acc[m][n]);
    }
    BAR2;
    cur ^= 1;
  }
#pragma unroll
  for (int m = 0; m < 4; m++)
#pragma unroll
    for (int n = 0; n < 2; n++)
#pragma unroll
      for (int j = 0; j < 4; j++) {
        int row = m0 + wm * 64 + m * 16 + (lane >> 4) * 4 + j;
        int col = n0 + wn * 32 + n * 16 + (lane & 15);
        dst[(size_t)row * DIN + col] = acc[m][n][j] + bias[col];
      }
}

// ============================================================================
// LayerNorm: writes z_e (fp32), z1 (f16 plane), znorm (row ||.||^2)
// ============================================================================
__global__ __launch_bounds__(256) void k_ln3(float* __restrict__ ze,
                                             const float* __restrict__ g,
                                             const float* __restrict__ b,
                                             f16* __restrict__ z1,
                                             float* __restrict__ znorm) {
  int t = threadIdx.x, lane = t & 63, wid = t >> 6;
  int R = blockIdx.x * 4 + wid;
  float* row = ze + (size_t)R * DM;
  float v[8];
  float s = 0.f, sq = 0.f;
#pragma unroll
  for (int j = 0; j < 8; j++) {
    v[j] = row[lane + j * 64];
    s += v[j];
    sq = fmaf(v[j], v[j], sq);
  }
#pragma unroll
  for (int m = 1; m < 64; m <<= 1) {
    s += __shfl_xor(s, m, 64);
    sq += __shfl_xor(sq, m, 64);
  }
  float mu = s * (1.f / DM);
  float var = sq * (1.f / DM) - mu * mu;
  float rs = rsqrtf(var + 1e-5f);
  float zn = 0.f;
#pragma unroll
  for (int j = 0; j < 8; j++) {
    int c = lane + j * 64;
    float o = (v[j] - mu) * rs * g[c] + b[c];
    row[c] = o;
    z1[(size_t)R * DM + c] = (f16)o;
    zn = fmaf(o, o, zn);
  }
#pragma unroll
  for (int m = 1; m < 64; m <<= 1) zn += __shfl_xor(zn, m, 64);
  if (lane == 0) znorm[R] = zn;
}

// ============================================================================
// EMA tail (proven): scan + deterministic commit reduce + chunked segment-sum
// ============================================================================
__global__ __launch_bounds__(1024) void k_scan(const int* __restrict__ counts,
                                               const float* __restrict__ cs_in,
                                               float* __restrict__ out,
                                               int* __restrict__ starts,
                                               int* __restrict__ offw,
                                               float* __restrict__ csd,
                                               const float* __restrict__ cpart,
                                               int* __restrict__ chpfx,
                                               int* __restrict__ chcode) {
  __shared__ float f[1024];
  __shared__ int ib[1024];
  int t = threadIdx.x;
  f[t] = cpart[t] + cpart[t + 1024];
  __syncthreads();
  for (int s = 512; s > 0; s >>= 1) {
    if (t < s) f[t] += f[t + s];
    __syncthreads();
  }
  if (t == 0) out[OFF_CL] = f[0] * (1.f / ((float)NROWS * (float)DM));
  __syncthreads();

  int cnt = counts[t];
  float ncs = 0.99f * cs_in[t] + 0.01f * (float)cnt;
  out[OFF_NCS + t] = ncs;
  f[t] = ncs;
  __syncthreads();
  for (int s = 512; s > 0; s >>= 1) {
    if (t < s) f[t] += f[t + s];
    __syncthreads();
  }
  float n = f[0];
  csd[t] = (ncs + 1e-5f) / (n + (float)KC * 1e-5f) * n;
  ib[t] = cnt;
  __syncthreads();
  for (int s = 1; s < 1024; s <<= 1) {
    int y = (t >= s) ? ib[t - s] : 0;
    __syncthreads();
    ib[t] += y;
    __syncthreads();
  }
  int excl = ib[t] - cnt;
  starts[t] = excl;
  offw[t] = excl;
  int nch = (cnt + CHSZ - 1) / CHSZ;
  __syncthreads();
  ib[t] = nch;
  __syncthreads();
  for (int s = 1; s < 1024; s <<= 1) {
    int y = (t >= s) ? ib[t - s] : 0;
    __syncthreads();
    ib[t] += y;
    __syncthreads();
  }
  int chx = ib[t] - nch;
  chpfx[t] = chx;
  if (t == KC - 1) chpfx[KC] = ib[t];
  for (int j = 0; j < nch; j++) chcode[chx + j] = t;
}

__global__ __launch_bounds__(256) void k_scatter(const int* __restrict__ idxws,
                                                 int* __restrict__ offw,
                                                 int* __restrict__ rowlist) {
  int r = blockIdx.x * 256 + threadIdx.x;
  int idx = idxws[r];
  int pos = atomicAdd(offw + idx, 1);
  rowlist[pos] = r;
}

__global__ __launch_bounds__(128) void k_partsum(const int* __restrict__ chpfx,
                                                 const int* __restrict__ chcode,
                                                 const int* __restrict__ starts,
                                                 const int* __restrict__ counts,
                                                 const int* __restrict__ rowlist,
                                                 const float* __restrict__ out,
                                                 float* __restrict__ part) {
  int c = blockIdx.x, t = threadIdx.x;
  if (c >= chpfx[KC]) return;
  int code = chcode[c];
  int j = c - chpfx[code];
  int ofs = starts[code] + j * CHSZ;
  int len = min(CHSZ, counts[code] - j * CHSZ);
  __shared__ int rl[CHSZ];
  if (t < len) rl[t] = rowlist[ofs + t];
  __syncthreads();
  const float* zeb = out + OFF_ZE;
  float a0 = 0.f, a1 = 0.f, a2 = 0.f, a3 = 0.f;
  for (int i = 0; i < len; i++) {
    const float* z = zeb + (size_t)rl[i] * DM;
    a0 += z[t];
    a1 += z[t + 128];
    a2 += z[t + 256];
    a3 += z[t + 384];
  }
  float* pp = part + (size_t)c * DM;
  pp[t] = a0;
  pp[t + 128] = a1;
  pp[t + 256] = a2;
  pp[t + 384] = a3;
}

__global__ __launch_bounds__(128) void k_codesum2(const int* __restrict__ chpfx,
                                                  const float* __restrict__ part,
                                                  const float* __restrict__ ema_in,
                                                  const float* __restrict__ csd,
                                                  float* __restrict__ out) {
  int k = blockIdx.x, t = threadIdx.x;
  int base = chpfx[k], nch = chpfx[k + 1] - base;
  float a0 = 0.f, a1 = 0.f, a2 = 0.f, a3 = 0.f;
  for (int i = 0; i < nch; i++) {
    const float* pp = part + (size_t)(base + i) * DM;
    a0 += pp[t];
    a1 += pp[t + 128];
    a2 += pp[t + 256];
    a3 += pp[t + 384];
  }
  float cs = csd[k];
  float sum[4] = {a0, a1, a2, a3};
#pragma unroll
  for (int j = 0; j < 4; j++) {
    int c = t + j * 128;
    float e = 0.99f * ema_in[(size_t)k * DM + c] + 0.01f * sum[j];
    out[OFF_NEMA + (size_t)k * DM + c] = e;
    out[OFF_NE + (size_t)k * DM + c] = e / cs;
  }
}

// ============================================================================
extern "C" void kernel_launch(void* const* d_in, const int* in_sizes, int n_in,
                              void* d_out, int out_size, void* d_ws, size_t ws_size,
                              hipStream_t stream) {
  (void)in_sizes; (void)n_in; (void)out_size; (void)ws_size;
  const float* x = (const float*)d_in[0];
  const float* enc_w = (const float*)d_in[1];
  const float* enc_b = (const float*)d_in[2];
  const float* ln_g = (const float*)d_in[3];
  const float* ln_b = (const float*)d_in[4];
  const float* dec_w = (const float*)d_in[5];
  const float* dec_b = (const float*)d_in[6];
  const float* emb = (const float*)d_in[7];
  const float* cs_in = (const float*)d_in[8];
  const float* ema_in = (const float*)d_in[9];
  float* out = (float*)d_out;
  char* ws = (char*)d_ws;
  float* znorm = (float*)(ws + WS_ZNORM);
  int* idxws = (int*)(ws + WS_IDX);
  int* counts = (int*)(ws + WS_COUNTS);
  int* starts = (int*)(ws + WS_STARTS);
  int* offw = (int*)(ws + WS_OFFW);
  int* rowlist = (int*)(ws + WS_ROWLIST);
  float* csd = (float*)(ws + WS_CSD);
  float* enorm = (float*)(ws + WS_ENORM);
  u64* cand = (u64*)(ws + WS2_CAND);
  f16* wt1 = (f16*)(ws + WS2_WT1);
  f16* wt2 = (f16*)(ws + WS2_WT2);
  f16* dT = (f16*)(ws + WS2_DT);
  f16* e1 = (f16*)(ws + WS2_E1);
  int* chpfx = (int*)(ws + WS3_CHPFX);
  int* chcode = (int*)(ws + WS3_CHCODE);
  float* cpart = (float*)(ws + WS3_CPART);
  float* part = (float*)(ws + WS3_PART);
  f16* z1 = (f16*)out;                 // scratch in x_recon region (overwritten by k_gdec3)

  k_init<<<dim3(4), dim3(256), 0, stream>>>(counts);
  k_prept<<<dim3(16, 32), dim3(256), 0, stream>>>(enc_w, wt1, wt2, DIN, DM);
  k_prept<<<dim3(32, 16), dim3(256), 0, stream>>>(dec_w, dT, nullptr, DM, DIN);
  k_prepe<<<dim3(512), dim3(256), 0, stream>>>(emb, e1);
  k_enorm<<<dim3(KC), dim3(64), 0, stream>>>(emb, enorm);
  k_genc2<<<dim3(1024), dim3(512), 0, stream>>>(x, wt1, wt2, enc_b, out + OFF_ZE);
  k_ln3<<<dim3(8192), dim3(256), 0, stream>>>(out + OFF_ZE, ln_g, ln_b, z1, znorm);
  k_dist3<<<dim3(2048), dim3(512), 0, stream>>>(z1, e1, enorm, cand);
  k_resolve<<<dim3(2048), dim3(256), 0, stream>>>(cand, znorm, enorm, emb, out,
                                                  idxws, counts, cpart);
  k_scan<<<dim3(1), dim3(1024), 0, stream>>>(counts, cs_in, out, starts, offw, csd,
                                             cpart, chpfx, chcode);
  k_scatter<<<dim3(NROWS / 256), dim3(256), 0, stream>>>(idxws, offw, rowlist);
  k_partsum<<<dim3(MAXCH), dim3(128), 0, stream>>>(chpfx, chcode, starts, counts,
                                                   rowlist, out, part);
  k_codesum2<<<dim3(KC), dim3(128), 0, stream>>>(chpfx, part, ema_in, csd, out);
  k_gdec3<<<dim3(2048), dim3(512), 0, stream>>>(e1, idxws, dT, dec_b, out + OFF_XR);
}